// Round 9
// baseline (179.731 us; speedup 1.0000x reference)
//
#include <hip/hip_runtime.h>

// Problem: B=64, C=3, S=384, P=32, R=169
//   out0: patches (B*R, C, P, P) f32 -> 33,226,752 elems
//   out1: pos     (B, R, 2)      f32 -> 21,632 elems (flat after patches)
//
// out[b,r,c,i,j] = bilinear sample of x[b,c,·,·] at
//   row = (j + crop_left[b,r]) * scale   (j = output fast axis)
//   col = (i + crop_top [b,r]) * scale ,  scale = 383/384.
// Verified R1-R8: 33-row window in-bounds, clamp never binds, absmax 0.016.
//
// R9: wave-autonomous, LDS-free. Math: y0(j) = floor((j+cl)s) - floor(cl*s)
// is ALWAYS j or j-1 (floor(frac(cl*s) - j/384) in {-1,0}; j/384 <= 0.081,
// margin >> f32 ulp). So a lane owning (column i, j-half h) keeps
// H[16h-1 .. 16h+16] (18 x-lerped row values) in STATIC registers and each
// output is a 2-way cndmask select + 2 fma. No LDS, no barriers, no DS pipe,
// no block lockstep: one wave per (patch, channel), 32448 independent waves.
#define Bn 64
#define Cn 3
#define Sn 384
#define Pn 32
#define Rn 169
#define PATCH_ELEMS (Cn * Pn * Pn)     // 3072
#define POS_OFFSET ((size_t)Bn * Rn * Cn * Pn * Pn)  // 33226752
#define PER_XCD 1352                   // 10816 / 8
#define UNITS_PER_XCD (PER_XCD * Cn)   // 4056 (patch,channel) units
#define BLOCKS_PER_XCD (UNITS_PER_XCD / 4)  // 1014 (4 waves per block)
#define SCALE (383.0f / 384.0f)
#define CSS (Cn * Sn * Sn)

typedef float f4 __attribute__((ext_vector_type(4)));

__global__ __launch_bounds__(256) void patch_kernel(
    const float* __restrict__ x,         // (B, C, S, S)
    const int*   __restrict__ crop_top,  // (B, R) -> column axis (i)
    const int*   __restrict__ crop_left, // (B, R) -> row axis (j)
    float*       __restrict__ out)
{
    // XCD partition: HW round-robins bid%8; sidx contiguous per XCD ->
    // consecutive units = same patch (channels) then next patch -> L2 local.
    const int bid  = blockIdx.x;
    const int xcd  = bid & 7;
    const int sidx = bid >> 3;           // 0..1013
    const int t    = threadIdx.x;
    const int w    = t >> 6;             // wave 0..3
    const int lane = t & 63;
    const int unit = sidx * 4 + w;       // 0..4055 (wave-uniform)
    const int prl  = unit / 3;           // patch within XCD
    const int c    = unit - prl * 3;     // channel
    const int pr   = xcd * PER_XCD + prl;
    const int b    = pr / Rn;

    const int i = lane & 31;             // output column (i axis)
    const int h = lane >> 5;             // j-half: j in [16h, 16h+16)

    const int ct = crop_top[pr];         // wave-uniform
    const int cl = crop_left[pr];
    const float ctf = (float)ct, clf = (float)cl;
    const int rb = (int)floorf(clf * SCALE);

    // x-weights for this lane's column
    float cx  = ((float)i + ctf) * SCALE;
    float fx  = floorf(cx);
    float wx  = cx - fx, owx = 1.0f - wx;
    // (int)fx <= 382; +1 <= 383 in-bounds. Lanes i consecutive -> the two
    // taps per row are one ~136B coalesced segment (2nd tap L1-hits).
    const float* base = x + (size_t)(b * CSS + c * (Sn * Sn)) + (int)fx;

    // ---- Load 18 rows x 2 taps into registers (36-deep MLP, static idx) ----
    // Rows r_first..r_first+17 where r_first = 16h-1: h=0 covers [-1..16]
    // (row -1 clamped; its H[0] is consumed only by j=0's never-taken false
    // path of the cndmask), h=1 covers [15..32]. Global row <= rb+32 <= 383.
    const int r_first = 16 * h - 1;
    float q0[18], q1[18];
    #pragma unroll
    for (int m = 0; m < 18; ++m) {
        int ro = r_first + m;
        ro = ro < 0 ? 0 : ro;            // only h=0, m=0
        const float* p = base + (rb + ro) * Sn;
        q0[m] = p[0];
        q1[m] = p[1];
    }

    // pos output rides in the load shadow (channel-0 waves, 2 lanes)
    if (c == 0 && lane < 2)
        out[POS_OFFSET + (size_t)pr * 2 + lane] = (lane == 0) ? ctf : clf;

    // ---- x-lerp into H registers ----
    float H[18];
    #pragma unroll
    for (int m = 0; m < 18; ++m)
        H[m] = owx * q0[m] + wx * q1[m];

    // ---- y-lerp + store: j = 16h + jj; y0 = rb+j (cond) or rb+j-1 ----
    // H index of absolute row y: y - (rb + 16h - 1) -> taps H[jj..jj+2].
    float* outp = out + (size_t)pr * PATCH_ELEMS + c * (Pn * Pn) + i * Pn + h * 16;
    const int jbase = 16 * h;
    #pragma unroll
    for (int s = 0; s < 4; ++s) {
        f4 v;
        #pragma unroll
        for (int e = 0; e < 4; ++e) {
            const int jj = s * 4 + e;    // static
            const int j  = jbase + jj;
            float cy  = ((float)j + clf) * SCALE;
            float fy  = floorf(cy);
            float wy  = cy - fy;
            float owy = 1.0f - wy;
            bool cond = ((int)fy == rb + j);          // y0 == j (else j-1)
            float a = cond ? H[jj + 1] : H[jj];       // v_cndmask, static idx
            float bb = cond ? H[jj + 2] : H[jj + 1];
            v[e] = owy * a + wy * bb;
        }
        // lane's 64B region at stride-64 across the wave; 4 back-to-back
        // 16B stores fill full 128B lines in L2 write-back before eviction.
        __builtin_nontemporal_store(v, (f4*)(outp + s * 4));
    }
}

extern "C" void kernel_launch(void* const* d_in, const int* in_sizes, int n_in,
                              void* d_out, int out_size, void* d_ws, size_t ws_size,
                              hipStream_t stream) {
    const float* x         = (const float*)d_in[0];
    const int*   crop_top  = (const int*)d_in[1];
    const int*   crop_left = (const int*)d_in[2];
    float*       out       = (float*)d_out;

    patch_kernel<<<dim3(8 * BLOCKS_PER_XCD), dim3(256), 0, stream>>>(
        x, crop_top, crop_left, out);
}

// Round 10
// 38.078 us; speedup vs baseline: 4.7201x; 4.7201x over previous
//
#include <hip/hip_runtime.h>

// Problem: B=64, C=3, S=384, P=32, R=169
//   out0: patches (B*R, C, P, P) f32 -> 33,226,752 elems
//   out1: pos     (B, R, 2)      f32 -> 21,632 elems (flat after patches)
//
// out[b,r,c,i,j] = bilinear sample of x[b,c,·,·] at
//   row = (j + crop_left[b,r]) * scale   (j = output fast axis)
//   col = (i + crop_top [b,r]) * scale
// scale = 383/384 < 1. Verified R1-R9: 33-row window at floor(crop*scale)
// always in-bounds; clamp never binds. absmax 0.016 vs thr 7.04.
//
// R10 = R7 (best, 37.48us) with ONE change: plain stores instead of
// nontemporal. R9 proved NT = L2-bypass (partial lines hit HBM unmerged,
// 340MB write amplification with scattered stores). Here stores are full-
// line contiguous either way; the A/B is whether L2 write-back (like the
// 7.2 TB/s fill kernel) schedules HBM writes better than NT streaming.
#define Bn 64
#define Cn 3
#define Sn 384
#define Pn 32
#define Rn 169
#define HROWS 33
#define HPLANE (Pn * HROWS)            // 1056 dwords per channel
#define PATCH_ELEMS (Cn * Pn * Pn)     // 3072
#define POS_OFFSET ((size_t)Bn * Rn * Cn * Pn * Pn)  // 33226752
#define NBLK (Bn * Rn)                 // 10816 = 8 * 1352
#define SCALE (383.0f / 384.0f)

typedef float f4 __attribute__((ext_vector_type(4)));

__global__ __launch_bounds__(256) void patch_kernel(
    const float* __restrict__ x,         // (B, C, S, S)
    const int*   __restrict__ crop_top,  // (B, R) -> column axis (i)
    const int*   __restrict__ crop_left, // (B, R) -> row axis (j)
    float*       __restrict__ out)
{
    // XCD-bijective swizzle (R2-R7: FETCH 48MB, good L2/L3 locality).
    const int bid = blockIdx.x;
    const int pr  = (bid & 7) * (NBLK / 8) + (bid >> 3);
    const int b   = pr / Rn;
    const int t   = threadIdx.x;

    // H[c][i][rr]: x-lerped window rows, stride 33. 12672 B LDS.
    __shared__ float H[Cn * HPLANE];

    const int ct = crop_top[pr];         // block-uniform -> s_load
    const int cl = crop_left[pr];
    const float ctf = (float)ct, clf = (float)cl;
    const int row_base = (int)floorf(clf * SCALE);

    // ---- Phase A: tap loads -> registers (24-deep MLP), then lerp -> LDS
    // Thread (i = t&31, g = t>>5) owns column i, rows 4g..4g+3.
    const int i = t & 31;
    const int g = t >> 5;
    float cx  = ((float)i + ctf) * SCALE;
    float fx  = floorf(cx);
    float wx  = cx - fx;
    float owx = 1.0f - wx;
    // x0a = (int)fx <= 382; +1 <= 383 in-bounds. Lanes i consecutive ->
    // each load instr is a coalesced ~128B segment.
    const float* basep = x + (size_t)b * (Cn * Sn * Sn) + (int)fx;
    const float* rp    = basep + (row_base + 4 * g) * Sn;

    // 1) issue all 24 loads into named registers (static indices -> VGPRs)
    float a0[Cn][4], a1[Cn][4];
    #pragma unroll
    for (int c = 0; c < Cn; ++c) {
        const float* p = rp + c * (Sn * Sn);
        #pragma unroll
        for (int k = 0; k < 4; ++k) {
            a0[c][k] = p[k * Sn];        // global_load_dword, imm offsets
            a1[c][k] = p[k * Sn + 1];
        }
    }
    // row 32 extra taps: threads 0..31 (divergent in wave 0 only; 6 loads)
    float e0[Cn], e1[Cn];
    if (t < 32) {
        const float* p = basep + (row_base + 32) * Sn;
        #pragma unroll
        for (int c = 0; c < Cn; ++c) {
            e0[c] = p[c * (Sn * Sn)];
            e1[c] = p[c * (Sn * Sn) + 1];
        }
    }
    // pos output rides in the load shadow
    if (t < 2) out[POS_OFFSET + (size_t)pr * 2 + t] = (t == 0) ? ctf : clf;

    // 2) x-lerp + LDS write, strictly after all loads are in flight.
    // Write bank = (33i + 4g + k)%32 = (i+4g+k)%32 -> exactly 2 lanes/bank
    // (free, m136); k=0..3 consecutive dwords -> 2x ds_write2_b32 per c.
    float* Hw = H + i * HROWS + 4 * g;
    #pragma unroll
    for (int c = 0; c < Cn; ++c) {
        #pragma unroll
        for (int k = 0; k < 4; ++k)
            Hw[c * HPLANE + k] = owx * a0[c][k] + wx * a1[c][k];
    }
    if (t < 32) {
        #pragma unroll
        for (int c = 0; c < Cn; ++c)
            H[c * HPLANE + t * HROWS + 32] = owx * e0[c] + wx * e1[c];
    }
    __syncthreads();

    // ---- Phase B: out(c,i,j) = owy*H[c][i][y0] + wy*H[c][i][y0+1] ----
    // Thread (jq = 4*(t&7), i2 = t>>3): ONE ds_read2 + 2 fma per output.
    // Read bank = (i2 + y0(jq+jj))%32 -> ~2 lanes/bank, free.
    const int jq = (t & 7) << 2;
    const int i2 = t >> 3;

    float wyv[4], owyv[4];
    int   yv[4];
    #pragma unroll
    for (int jj = 0; jj < 4; ++jj) {
        float cy = ((float)(jq + jj) + clf) * SCALE;
        float fy = floorf(cy);
        wyv[jj]  = cy - fy;
        owyv[jj] = 1.0f - wyv[jj];
        yv[jj]   = (int)fy - row_base;   // in [0,31]; +1 <= 32 < HROWS
    }

    float* outp = out + (size_t)pr * PATCH_ELEMS + i2 * Pn + jq;

    #pragma unroll
    for (int c = 0; c < Cn; ++c) {
        const float* Hc = H + c * HPLANE + i2 * HROWS;
        f4 v;
        #pragma unroll
        for (int jj = 0; jj < 4; ++jj) {
            float h0 = Hc[yv[jj]];       // } ds_read2_b32 (offsets 0,1)
            float h1 = Hc[yv[jj] + 1];   // }
            v[jj] = owyv[jj] * h0 + wyv[jj] * h1;
        }
        // wave = 8 i2-groups x 8 jq-lanes x 16B = 1KB contiguous.
        // R10 A/B: PLAIN store (L2 write-back, like the 7.2 TB/s fill)
        // instead of nontemporal (L2-bypass streaming).
        *(f4*)(outp + c * (Pn * Pn)) = v;
    }
}

extern "C" void kernel_launch(void* const* d_in, const int* in_sizes, int n_in,
                              void* d_out, int out_size, void* d_ws, size_t ws_size,
                              hipStream_t stream) {
    const float* x         = (const float*)d_in[0];
    const int*   crop_top  = (const int*)d_in[1];
    const int*   crop_left = (const int*)d_in[2];
    float*       out       = (float*)d_out;

    patch_kernel<<<dim3(NBLK), dim3(256), 0, stream>>>(x, crop_top, crop_left, out);
}